// Round 2
// baseline (2568.640 us; speedup 1.0000x reference)
//
#include <hip/hip_runtime.h>
#include <math.h>

#define BATCH 8
#define WID   32
#define NX    64
#define NY    64
#define NT    40
#define M1C   12
#define KT    8      // M3
#define KXC   24
#define KYC   24
#define NXY   (NX*NY)        // 4096
#define NXYT  (NXY*NT)       // 163840
#define NP    (BATCH*NXYT)   // 1310720

#define TWO_PI 6.283185307179586f

static __device__ __forceinline__ float gelu_f(float v){
  return 0.5f*v*(1.0f + erff(v*0.7071067811865476f));
}

// ---------------- fc0: [B,X,Y,T,5] -> V [B,32,X,Y,T] ----------------
__global__ __launch_bounds__(256) void k_fc0(const float* __restrict__ h, const float* __restrict__ x,
                                             const float* __restrict__ w, const float* __restrict__ b,
                                             float* __restrict__ V){
  int p = blockIdx.x*256 + threadIdx.x;
  if(p >= NP) return;
  int bi = p / NXYT, xyt = p - bi*NXYT;
  float i0 = h[(size_t)p*2+0], i1 = h[(size_t)p*2+1];
  float i2 = x[(size_t)p*3+0], i3 = x[(size_t)p*3+1], i4 = x[(size_t)p*3+2];
  #pragma unroll
  for(int c=0;c<WID;c++){
    float v = b[c] + i0*w[c] + i1*w[32+c] + i2*w[64+c] + i3*w[96+c] + i4*w[128+c];
    V[((size_t)(bi*WID+c))*NXYT + xyt] = v;
  }
}

// ------- fused forward T+Y: V[b,c,x,:,:] -> F2 [bc*64+x][ky*8+kt] -------
__global__ __launch_bounds__(256) void k_fwd_ty(const float* __restrict__ V, float2* __restrict__ F2){
  __shared__ float  vt[NY*NT];          // 2560 floats
  __shared__ float2 f1[NY*KT];          // 512 cplx
  __shared__ float  tc[KT*NT], ts[KT*NT];
  __shared__ float  yc[KYC*NY], ys[KYC*NY];
  int tid = threadIdx.x;
  size_t base = (size_t)blockIdx.x * (NY*NT);
  for(int i=tid;i<NY*NT;i+=256) vt[i] = V[base + i];
  for(int i=tid;i<KT*NT;i+=256){
    int k=i/NT, t=i-k*NT;
    float ang = -TWO_PI*(float)((k*t)%NT)/(float)NT;
    tc[i]=cosf(ang); ts[i]=sinf(ang);
  }
  for(int i=tid;i<KYC*NY;i+=256){
    int ky=i/NY, y=i-ky*NY;
    int f = ky<M1C ? ky : ky+40;
    float ang = -TWO_PI*(float)((f*y)%NY)/(float)NY;
    yc[i]=cosf(ang); ys[i]=sinf(ang);
  }
  __syncthreads();
  for(int item=tid; item<NY*KT; item+=256){
    int y=item>>3, k=item&7;
    float sr=0.f, si=0.f;
    #pragma unroll
    for(int t=0;t<NT;t++){ float v=vt[y*NT+t]; sr+=v*tc[k*NT+t]; si+=v*ts[k*NT+t]; }
    f1[item]=make_float2(sr,si);
  }
  __syncthreads();
  if(tid < KYC*KT){
    int ky=tid>>3, kt=tid&7;
    float sr=0.f, si=0.f;
    #pragma unroll 8
    for(int y=0;y<NY;y++){
      float2 a=f1[y*KT+kt];
      float c=yc[ky*NY+y], s=ys[ky*NY+y];
      sr += a.x*c - a.y*s;
      si += a.x*s + a.y*c;
    }
    F2[(size_t)blockIdx.x*(KYC*KT) + tid] = make_float2(sr,si);
  }
}

// ---------------- forward X: F2 -> F3 [B,32,24,24,8] cplx ----------------
__global__ __launch_bounds__(256) void k_fwd_x(const float2* __restrict__ F2, float2* __restrict__ F3){
  __shared__ float2 tile[NX*KT];
  __shared__ float twc[KXC*NX], tws[KXC*NX];
  int tid=threadIdx.x;
  int bc = blockIdx.x / KYC;                 // [0,256)
  int ky = blockIdx.x - bc*KYC;
  for(int i=tid;i<NX*KT;i+=256){
    int xx=i/KT, kt=i-xx*KT;
    tile[i] = F2[((size_t)bc*NX + xx)*(KYC*KT) + ky*KT + kt];
  }
  for(int i=tid;i<KXC*NX;i+=256){
    int kx=i/NX, xx=i-kx*NX;
    int f = kx<M1C ? kx : kx+40;
    float ang = -TWO_PI*(float)((f*xx)%NX)/(float)NX;
    twc[i]=cosf(ang); tws[i]=sinf(ang);
  }
  __syncthreads();
  for(int item=tid; item<KXC*KT; item+=256){
    int kx=item/KT, kt=item-kx*KT;
    float sr=0.f, si=0.f;
    #pragma unroll 8
    for(int xx=0;xx<NX;xx++){
      float2 a = tile[xx*KT+kt];
      float c = twc[kx*NX+xx], s = tws[kx*NX+xx];
      sr += a.x*c - a.y*s;
      si += a.x*s + a.y*c;
    }
    F3[(size_t)bc*(KXC*KYC*KT) + kx*(KYC*KT) + ky*KT + kt] = make_float2(sr,si);
  }
}

// ---------------- channel mix: F3 -> F4 ----------------
__global__ __launch_bounds__(256) void k_mix(const float2* __restrict__ F3, const float* __restrict__ wr,
                                             const float* __restrict__ wi, float2* __restrict__ F4){
  int idx = blockIdx.x*256 + threadIdx.x;    // < 8*32*4608
  int b = idx / (WID*4608);
  int r = idx - b*(WID*4608);
  int o = r / 4608;
  int mode = r - o*4608;
  int kx = mode/192;
  int ky = (mode/KT)%KYC;
  int kt = mode & 7;
  int xp = (kx>=M1C), yp = (ky>=M1C);
  int m1 = kx - M1C*xp, m2 = ky - M1C*yp;
  int blk = xp + 2*yp;
  // weight index = ((((blk*32+i)*32+o)*12+m1)*12+m2)*8+kt
  size_t widx = (size_t)blk*1179648 + (size_t)o*1152 + m1*96 + m2*8 + kt;
  const float2* src = F3 + (size_t)b*WID*4608 + mode;
  float ar=0.f, ai=0.f;
  #pragma unroll 8
  for(int i=0;i<WID;i++){
    float2 a = src[(size_t)i*4608];
    float r_ = wr[widx], q_ = wi[widx];
    ar += a.x*r_ - a.y*q_;
    ai += a.x*q_ + a.y*r_;
    widx += 36864;
  }
  F4[((size_t)b*WID + o)*4608 + mode] = make_float2(ar, ai);
}

// ---------------- inverse X: F4 -> F2 (1/64 folded) ----------------
__global__ __launch_bounds__(256) void k_inv_x(const float2* __restrict__ F4, float2* __restrict__ F2){
  __shared__ float2 tile[KXC*KT];
  __shared__ float twc[NX*KXC], tws[NX*KXC];
  int tid=threadIdx.x;
  int bc = blockIdx.x / KYC, ky = blockIdx.x - (blockIdx.x/KYC)*KYC;
  for(int i=tid;i<KXC*KT;i+=256){
    int kx=i/KT, kt=i-kx*KT;
    tile[i] = F4[(size_t)bc*4608 + kx*(KYC*KT) + ky*KT + kt];
  }
  for(int i=tid;i<NX*KXC;i+=256){
    int xx=i/KXC, kx=i-xx*KXC;
    int f = kx<M1C ? kx : kx+40;
    float ang = TWO_PI*(float)((f*xx)%NX)/(float)NX;
    twc[i]=cosf(ang)*(1.0f/64.0f); tws[i]=sinf(ang)*(1.0f/64.0f);
  }
  __syncthreads();
  for(int item=tid; item<NX*KT; item+=256){
    int xx=item/KT, kt=item-xx*KT;
    float sr=0.f, si=0.f;
    #pragma unroll 8
    for(int kx=0;kx<KXC;kx++){
      float2 a = tile[kx*KT+kt];
      float c = twc[xx*KXC+kx], s = tws[xx*KXC+kx];
      sr += a.x*c - a.y*s;
      si += a.x*s + a.y*c;
    }
    F2[((size_t)bc*NX + xx)*(KYC*KT) + ky*KT + kt] = make_float2(sr,si);
  }
}

// ------- fused inv-Y + irfft-T + conv1x1 [+gelu], in-place on V -------
// one block per (b,x); loops y = 0..63
template<bool GELU>
__global__ __launch_bounds__(256) void k_inv_y_conv(const float2* __restrict__ F2, const float* __restrict__ wcv,
                                                    const float* __restrict__ bcv, float* __restrict__ Vio){
  __shared__ float2 f2s[WID*KYC*KT];   // 6144 cplx = 48 KiB
  __shared__ float  wm[WID*WID];
  __shared__ float  bb[WID];
  __shared__ float  tc[KT*NT], ts[KT*NT];   // w_k/40 folded
  __shared__ float  vt[WID*NT];
  __shared__ float2 ft[WID*KT];
  __shared__ float2 twy[KYC];
  int tid=threadIdx.x;
  int b = blockIdx.x >> 6, x = blockIdx.x & 63;
  for(int i=tid;i<WID*KYC*KT;i+=256){
    int c=i/(KYC*KT), j=i-c*(KYC*KT);
    f2s[i] = F2[((size_t)(b*WID+c)*NX + x)*(KYC*KT) + j];
  }
  for(int i=tid;i<WID*WID;i+=256) wm[i]=wcv[i];
  if(tid<WID) bb[tid]=bcv[tid];
  for(int i=tid;i<KT*NT;i+=256){
    int k=i/NT, t=i-k*NT;
    float ang = TWO_PI*(float)((k*t)%NT)/(float)NT;
    float sc = (k==0 ? 1.0f : 2.0f)*(1.0f/(float)NT);
    tc[i]=cosf(ang)*sc; ts[i]=sinf(ang)*sc;
  }
  __syncthreads();
  for(int y=0;y<NY;y++){
    for(int i=tid;i<WID*NT;i+=256){
      int c=i/NT, t=i-c*NT;
      vt[i] = Vio[((size_t)(b*WID+c)*NXY + x*NY + y)*NT + t];
    }
    if(tid<KYC){
      int f = tid<M1C ? tid : tid+40;
      float ang = TWO_PI*(float)((f*y)%NY)/(float)NY;
      twy[tid] = make_float2(cosf(ang)*(1.0f/(float)NY), sinf(ang)*(1.0f/(float)NY));
    }
    __syncthreads();
    { // ft[c][kt]: exactly 256 items
      int c=tid>>3, kt=tid&7;
      float sr=0.f, si=0.f;
      #pragma unroll 8
      for(int ky=0;ky<KYC;ky++){
        float2 a=f2s[c*(KYC*KT) + ky*KT + kt];
        float2 w=twy[ky];
        sr += a.x*w.x - a.y*w.y;
        si += a.x*w.y + a.y*w.x;
      }
      ft[tid]=make_float2(sr,si);
    }
    __syncthreads();
    for(int item=tid; item<WID*NT; item+=256){
      int o=item/NT, t=item-o*NT;
      float acc = bb[o];
      #pragma unroll 8
      for(int c=0;c<WID;c++) acc += vt[c*NT+t]*wm[o*WID+c];
      float spec=0.f;
      #pragma unroll
      for(int k=0;k<KT;k++){
        float2 a = ft[o*KT+k];
        spec += a.x*tc[k*NT+t] - a.y*ts[k*NT+t];
      }
      float v = acc + spec;
      if(GELU) v = gelu_f(v);
      Vio[((size_t)(b*WID+o)*NXY + x*NY + y)*NT + t] = v;
    }
    __syncthreads();
  }
}

// ---------------- fused fc1+gelu+fc2: V -> out [B,X,Y,T,2] ----------------
__global__ __launch_bounds__(64) void k_mlp(const float* __restrict__ Vin, const float* __restrict__ w1,
                                            const float* __restrict__ b1, const float* __restrict__ w2,
                                            const float* __restrict__ b2, float* __restrict__ out){
  __shared__ float vt[WID*NT];
  __shared__ float sw1[WID*64];
  __shared__ float sb1[64];
  __shared__ float sw2[128];
  __shared__ float sb2[2];
  int tid=threadIdx.x;
  int b  = blockIdx.x >> 12;
  int xy = blockIdx.x & 4095;
  for(int i=tid;i<WID*NT;i+=64){
    int c=i/NT, t=i-c*NT;
    vt[i] = Vin[((size_t)(b*WID+c))*NXYT + xy*NT + t];
  }
  for(int i=tid;i<WID*64;i+=64) sw1[i]=w1[i];
  sb1[tid]=b1[tid];
  for(int i=tid;i<128;i+=64) sw2[i]=w2[i];
  if(tid<2) sb2[tid]=b2[tid];
  __syncthreads();
  if(tid<NT){
    float vcol[WID];
    #pragma unroll
    for(int c=0;c<WID;c++) vcol[c]=vt[c*NT+tid];
    float o0=sb2[0], o1=sb2[1];
    #pragma unroll 4
    for(int j=0;j<64;j++){
      float a = sb1[j];
      #pragma unroll
      for(int c=0;c<WID;c++) a += vcol[c]*sw1[c*64+j];
      a = gelu_f(a);
      o0 += a*sw2[j*2+0];
      o1 += a*sw2[j*2+1];
    }
    size_t p = ((size_t)(b*NXY + xy))*NT + tid;
    out[p*2+0]=o0;
    out[p*2+1]=o1;
  }
}

extern "C" void kernel_launch(void* const* d_in, const int* in_sizes, int n_in,
                              void* d_out, int out_size, void* d_ws, size_t ws_size,
                              hipStream_t stream){
  const float* h     = (const float*)d_in[0];
  const float* x     = (const float*)d_in[1];
  const float* fc0_w = (const float*)d_in[2];
  const float* fc0_b = (const float*)d_in[3];
  const float* scwr[3] = {(const float*)d_in[4], (const float*)d_in[6], (const float*)d_in[8]};
  const float* scwi[3] = {(const float*)d_in[5], (const float*)d_in[7], (const float*)d_in[9]};
  const float* cw[3]   = {(const float*)d_in[10], (const float*)d_in[12], (const float*)d_in[14]};
  const float* cb[3]   = {(const float*)d_in[11], (const float*)d_in[13], (const float*)d_in[15]};
  const float* fc1_w = (const float*)d_in[16];
  const float* fc1_b = (const float*)d_in[17];
  const float* fc2_w = (const float*)d_in[18];
  const float* fc2_b = (const float*)d_in[19];

  // workspace: V (167.8 MB) | F2 (25.2 MB) | F4 (9.4 MB)  == 202 MB total
  // F3 lives in d_out (9.4 MB <= 10.5 MB) until k_mlp overwrites it at the end.
  const size_t VSZ = (size_t)BATCH*WID*NXYT;          // 41,943,040 floats
  float*  V  = (float*)d_ws;
  float2* F2 = (float2*)(V + VSZ);                    // B*32*64*24*8 = 3,145,728 cplx
  float2* F4 = F2 + (size_t)BATCH*WID*NX*KYC*KT;      // B*32*24*24*8 = 1,179,648 cplx
  float2* F3 = (float2*)d_out;                        // scratch until final k_mlp

  k_fc0<<<NP/256, 256, 0, stream>>>(h, x, fc0_w, fc0_b, V);
  for(int L=0; L<3; L++){
    k_fwd_ty<<<BATCH*WID*NX, 256, 0, stream>>>(V, F2);
    k_fwd_x<<<(BATCH*WID)*KYC, 256, 0, stream>>>(F2, F3);
    k_mix<<<(BATCH*WID*KXC*KYC*KT)/256, 256, 0, stream>>>(F3, scwr[L], scwi[L], F4);
    k_inv_x<<<(BATCH*WID)*KYC, 256, 0, stream>>>(F4, F2);
    if(L<2) k_inv_y_conv<true ><<<BATCH*NX, 256, 0, stream>>>(F2, cw[L], cb[L], V);
    else    k_inv_y_conv<false><<<BATCH*NX, 256, 0, stream>>>(F2, cw[L], cb[L], V);
  }
  k_mlp<<<BATCH*NXY, 64, 0, stream>>>(V, fc1_w, fc1_b, fc2_w, fc2_b, (float*)d_out);
}